// Round 1
// 384.487 us; speedup vs baseline: 1.0642x; 1.0642x over previous
//
#include <hip/hip_runtime.h>
#include <math.h>

// B=512, IN_CORES=12, N_PRIM=12, N_PAR=10, RFPC=4, RF=64, CAP=256
// out = concat( sigmoid MLP output (512,3072) f32 , x_sum (512,2560) f32 )
// C1/C_skip/C2 are Bernoulli 0/1 -> routing einsum is sparse sum-pooling.
//
// R1 changes vs baseline (409 us):
//  1. convT_all: latency-bound (VALUBusy 11%, HBM 26%, Mfma 0) -> software
//     pipeline 4 tiles/block with LDS double-buffer (load regs i+1 || pack i).
//  2. MLP layer 1: x_recon has ONE nonzero 256-capsule per row -> bucket rows
//     by argmax capsule, grouped GEMM K=256 (10x fewer FLOPs), fused
//     bias+relu epilogue (no split-K, no Pbuf round-trip). Row permutation is
//     carried through layers 2/3 and undone in the final sigmoid combine.

#define BATCH 512
#define OUT0_SZ (512*3072)

typedef __attribute__((ext_vector_type(8))) short short8;   // 8 x bf16
typedef __attribute__((ext_vector_type(4))) float f32x4;

__device__ inline unsigned short f2bf(float f) {
    union { float f; unsigned u; } v; v.f = f;
    unsigned r = v.u + 0x7fffu + ((v.u >> 16) & 1u);   // RNE
    return (unsigned short)(r >> 16);
}
__device__ inline float bf2f(unsigned int hi16) {       // low 16 bits = bf16
    union { unsigned u; float f; } v; v.u = hi16 << 16; return v.f;
}

// async global->LDS, 16 bytes per lane
#define GLD16(g, l) __builtin_amdgcn_global_load_lds( \
    (const __attribute__((address_space(1))) unsigned int*)(g), \
    (__attribute__((address_space(3))) unsigned int*)(l), 16, 0, 0)

// ---------------------------------------------------------------------------
// Prep: MLP weight convert+transpose (f32 [K][N] -> bf16 [N][K], padded)
// + capsule weight transpose W1/W2.  4 tiles per block, double-buffered LDS
// software pipeline: global loads for tile i+1 issue before pack/store of
// tile i -> HBM latency hidden under pack work (was latency-bound at 26% BW).
//   tiles: L1 40x80=3200 | L2 80x64=5120 | L3 64x48=3072 | W1t 48 | W2t 40
// ---------------------------------------------------------------------------
struct CTJob {
    const float* W; unsigned short* Wt;
    int Kr, Nr, Kp, k0, n0;
};

__device__ inline CTJob ct_resolve(int bid,
    const float* Wr1, unsigned short* Wt1,
    const float* Wr2, unsigned short* Wt2,
    const float* Wr3, unsigned short* Wt3,
    const float* W1,  unsigned short* W1t,
    const float* W2,  unsigned short* W2t)
{
    CTJob j;
    int ktiles, rem;
    if (bid < 3200)       { j.W = Wr1; j.Wt = Wt1; j.Kr = 2560; j.Nr = 5000; j.Kp = 2560; ktiles = 40; rem = bid; }
    else if (bid < 8320)  { j.W = Wr2; j.Wt = Wt2; j.Kr = 5000; j.Nr = 4000; j.Kp = 5120; ktiles = 80; rem = bid - 3200; }
    else if (bid < 11392) { j.W = Wr3; j.Wt = Wt3; j.Kr = 4000; j.Nr = 3072; j.Kp = 4096; ktiles = 64; rem = bid - 8320; }
    else if (bid < 11440) { int kl = bid - 11392; j.W = W1 + (size_t)kl * 4096; j.Wt = W1t + (size_t)kl * 4096;
                            j.Kr = 64; j.Nr = 64; j.Kp = 64; ktiles = 1; rem = 0; }
    else                  { int kl = bid - 11440; j.W = W2 + (size_t)kl * 4096; j.Wt = W2t + (size_t)kl * 4096;
                            j.Kr = 64; j.Nr = 64; j.Kp = 64; ktiles = 1; rem = 0; }
    j.k0 = (rem % ktiles) * 64;
    j.n0 = (rem / ktiles) * 64;
    return j;
}

__device__ inline void ct_load(const CTJob& j, int tid, float4* v) {
    int kr = tid >> 4;
    int nc = (tid & 15) * 4;
    #pragma unroll
    for (int p = 0; p < 4; ++p) {
        int k = j.k0 + kr + p * 16;
        float4 vv = make_float4(0.f, 0.f, 0.f, 0.f);
        if (k < j.Kr) {
            if (j.n0 + nc + 3 < j.Nr) {
                vv = *(const float4*)&j.W[(size_t)k * j.Nr + j.n0 + nc];
            } else {
                float tmp[4] = {0.f, 0.f, 0.f, 0.f};
                #pragma unroll
                for (int jj = 0; jj < 4; ++jj)
                    if (j.n0 + nc + jj < j.Nr) tmp[jj] = j.W[(size_t)k * j.Nr + j.n0 + nc + jj];
                vv = make_float4(tmp[0], tmp[1], tmp[2], tmp[3]);
            }
        }
        v[p] = vv;
    }
}

__device__ inline void ct_stlds(float* t, int tid, const float4* v) {
    int kr = tid >> 4;
    int nc = (tid & 15) * 4;
    #pragma unroll
    for (int p = 0; p < 4; ++p) {
        float* row = &t[(kr + p * 16) * 65 + nc];
        row[0] = v[p].x; row[1] = v[p].y; row[2] = v[p].z; row[3] = v[p].w;
    }
}

__device__ inline void ct_pack(const CTJob& j, const float* t, int tid) {
    int nr = tid >> 2;
    int kc = (tid & 3) * 16;
    unsigned int u[8];
    #pragma unroll
    for (int jj = 0; jj < 8; ++jj) {
        float v0 = t[(kc + 2 * jj)     * 65 + nr];
        float v1 = t[(kc + 2 * jj + 1) * 65 + nr];
        u[jj] = (unsigned int)f2bf(v0) | ((unsigned int)f2bf(v1) << 16);
    }
    unsigned int* dst = (unsigned int*)&j.Wt[(size_t)(j.n0 + nr) * j.Kp + j.k0 + kc];
    *(uint4*)(dst)     = make_uint4(u[0], u[1], u[2], u[3]);
    *(uint4*)(dst + 4) = make_uint4(u[4], u[5], u[6], u[7]);
}

__global__ __launch_bounds__(256) void convT_all(
    const float* __restrict__ Wr1, unsigned short* __restrict__ Wt1,
    const float* __restrict__ Wr2, unsigned short* __restrict__ Wt2,
    const float* __restrict__ Wr3, unsigned short* __restrict__ Wt3,
    const float* __restrict__ W1,  unsigned short* __restrict__ W1t,
    const float* __restrict__ W2,  unsigned short* __restrict__ W2t)
{
    __shared__ float t[2][64 * 65];
    int tid = threadIdx.x;
    int tbase = blockIdx.x * 4;

    CTJob jc = ct_resolve(tbase, Wr1, Wt1, Wr2, Wt2, Wr3, Wt3, W1, W1t, W2, W2t);
    float4 v[4];
    ct_load(jc, tid, v);
    ct_stlds(t[0], tid, v);
    __syncthreads();

    #pragma unroll
    for (int i = 0; i < 4; ++i) {
        CTJob jn;
        float4 vn[4];
        if (i < 3) {
            jn = ct_resolve(tbase + i + 1, Wr1, Wt1, Wr2, Wt2, Wr3, Wt3, W1, W1t, W2, W2t);
            ct_load(jn, tid, vn);          // global loads in flight...
        }
        ct_pack(jc, t[i & 1], tid);        // ...hidden under pack + store
        if (i < 3) {
            ct_stlds(t[(i + 1) & 1], tid, vn);
            jc = jn;
        }
        __syncthreads();
    }
}

// ---------------------------------------------------------------------------
// Capsule layer 1 as pooled MFMA GEMM. Grid (48 kl, 4 m-tiles), 256 thr.
// ---------------------------------------------------------------------------
__global__ __launch_bounds__(256) void caps_gemm1(
    const float* __restrict__ x, const float* __restrict__ C1,
    const unsigned short* __restrict__ W1t, const float* __restrict__ b1,
    unsigned short* __restrict__ xp)
{
    __shared__ __align__(16) unsigned short As[128 * 72];
    __shared__ __align__(16) unsigned short Bs[64 * 72];
    __shared__ float Csh[48];
    int kl = blockIdx.x;
    int bm = blockIdx.y * 128;
    int tid = threadIdx.x;
    int w = tid >> 6, lane = tid & 63, q = lane >> 4, r16 = lane & 15;
    int wm = (w >> 1) * 64, wn = (w & 1) * 32;

    if (tid < 48) Csh[tid] = C1[tid * 48 + kl];
    {   // stage B = W1t[kl], 64x64 bf16, padded stride 72
        const uint4* src = (const uint4*)(W1t + (size_t)kl * 4096);
        #pragma unroll
        for (int p = 0; p < 2; ++p) {
            int c = tid + p * 256;
            int row = c >> 3, cq = c & 7;
            *(uint4*)&Bs[row * 72 + cq * 8] = src[c];
        }
    }
    __syncthreads();

    // A-pool: thread -> (row = tid>>1, 32-col half)
    int arow = tid >> 1, ah = (tid & 1) * 32;
    float accp[32];
    #pragma unroll
    for (int i = 0; i < 32; ++i) accp[i] = 0.f;
    const float* xrow = x + (size_t)(bm + arow) * 3072 + ah;
    for (int ij = 0; ij < 48; ++ij) {
        float c = Csh[ij];
        if (c != 0.f) {
            const float4* p4 = (const float4*)(xrow + ij * 64);
            #pragma unroll
            for (int cc = 0; cc < 8; ++cc) {
                float4 v = p4[cc];
                accp[cc * 4 + 0] = fmaf(c, v.x, accp[cc * 4 + 0]);
                accp[cc * 4 + 1] = fmaf(c, v.y, accp[cc * 4 + 1]);
                accp[cc * 4 + 2] = fmaf(c, v.z, accp[cc * 4 + 2]);
                accp[cc * 4 + 3] = fmaf(c, v.w, accp[cc * 4 + 3]);
            }
        }
    }
    {   // pack -> As
        unsigned short* dst = &As[arow * 72 + ah];
        #pragma unroll
        for (int cc = 0; cc < 4; ++cc) {
            unsigned int u[4];
            #pragma unroll
            for (int j = 0; j < 4; ++j)
                u[j] = (unsigned int)f2bf(accp[cc * 8 + 2 * j]) |
                       ((unsigned int)f2bf(accp[cc * 8 + 2 * j + 1]) << 16);
            *(uint4*)&dst[cc * 8] = make_uint4(u[0], u[1], u[2], u[3]);
        }
    }
    __syncthreads();

    f32x4 acc[4][2];
    #pragma unroll
    for (int i = 0; i < 4; ++i)
        #pragma unroll
        for (int j = 0; j < 2; ++j) acc[i][j] = (f32x4)0.f;
    #pragma unroll
    for (int ks = 0; ks < 2; ++ks) {
        short8 a[4], b[2];
        #pragma unroll
        for (int mt = 0; mt < 4; ++mt)
            a[mt] = *(const short8*)&As[(wm + mt * 16 + r16) * 72 + ks * 32 + q * 8];
        #pragma unroll
        for (int nt = 0; nt < 2; ++nt)
            b[nt] = *(const short8*)&Bs[(wn + nt * 16 + r16) * 72 + ks * 32 + q * 8];
        #pragma unroll
        for (int mt = 0; mt < 4; ++mt)
            #pragma unroll
            for (int nt = 0; nt < 2; ++nt)
                acc[mt][nt] = __builtin_amdgcn_mfma_f32_16x16x32_bf16(a[mt], b[nt], acc[mt][nt], 0, 0, 0);
    }

    #pragma unroll
    for (int mt = 0; mt < 4; ++mt) {
        #pragma unroll
        for (int nt = 0; nt < 2; ++nt) {
            int n = wn + nt * 16 + r16;
            float bv = b1[kl * 64 + n];
            #pragma unroll
            for (int reg = 0; reg < 4; ++reg) {
                int row = bm + wm + mt * 16 + q * 4 + reg;
                xp[(size_t)row * 3072 + kl * 64 + n] = f2bf(fmaxf(acc[mt][nt][reg] + bv, 0.f));
            }
        }
    }
}

// ---------------------------------------------------------------------------
// Capsule layer 2 + skip + norms. Grid (40 kl, 4 m-tiles), 256 thr.
// ---------------------------------------------------------------------------
__global__ __launch_bounds__(256) void caps_gemm2(
    const unsigned short* __restrict__ xp, const float* __restrict__ Cs,
    const float* __restrict__ C2, const unsigned short* __restrict__ W2t,
    const float* __restrict__ b2, float* __restrict__ xsum,
    float* __restrict__ part8)
{
    __shared__ __align__(16) unsigned short As[128 * 72];
    __shared__ __align__(16) unsigned short Bs[64 * 72];
    __shared__ __align__(16) float Sk[128 * 68];
    __shared__ float C2sh[48], Cssh[48];
    int kl = blockIdx.x;
    int bm = blockIdx.y * 128;
    int tid = threadIdx.x;
    int w = tid >> 6, lane = tid & 63, q = lane >> 4, r16 = lane & 15;
    int wm = (w >> 1) * 64, wn = (w & 1) * 32;
    int half = w & 1;

    if (tid < 48) { C2sh[tid] = C2[tid * 40 + kl]; Cssh[tid] = Cs[tid * 40 + kl]; }
    {
        const uint4* src = (const uint4*)(W2t + (size_t)kl * 4096);
        #pragma unroll
        for (int p = 0; p < 2; ++p) {
            int c = tid + p * 256;
            int row = c >> 3, cq = c & 7;
            *(uint4*)&Bs[row * 72 + cq * 8] = src[c];
        }
    }
    __syncthreads();

    int arow = tid >> 1, ah = (tid & 1) * 32;
    float accp[32], skp[32];
    #pragma unroll
    for (int i = 0; i < 32; ++i) { accp[i] = 0.f; skp[i] = 0.f; }
    const unsigned short* xprow = xp + (size_t)(bm + arow) * 3072 + ah;
    for (int ij = 0; ij < 48; ++ij) {
        float c2 = C2sh[ij], cs = Cssh[ij];
        if (c2 != 0.f || cs != 0.f) {
            const uint4* p4 = (const uint4*)(xprow + ij * 64);
            #pragma unroll
            for (int cc = 0; cc < 4; ++cc) {
                uint4 v = p4[cc];
                unsigned int uu[4] = {v.x, v.y, v.z, v.w};
                #pragma unroll
                for (int j = 0; j < 4; ++j) {
                    float lo = bf2f(uu[j] & 0xffffu);
                    float hi = bf2f(uu[j] >> 16);
                    int idx = cc * 8 + 2 * j;
                    accp[idx]     = fmaf(c2, lo, accp[idx]);
                    accp[idx + 1] = fmaf(c2, hi, accp[idx + 1]);
                    skp[idx]      = fmaf(cs, lo, skp[idx]);
                    skp[idx + 1]  = fmaf(cs, hi, skp[idx + 1]);
                }
            }
        }
    }
    {
        unsigned short* dst = &As[arow * 72 + ah];
        #pragma unroll
        for (int cc = 0; cc < 4; ++cc) {
            unsigned int u[4];
            #pragma unroll
            for (int j = 0; j < 4; ++j)
                u[j] = (unsigned int)f2bf(accp[cc * 8 + 2 * j]) |
                       ((unsigned int)f2bf(accp[cc * 8 + 2 * j + 1]) << 16);
            *(uint4*)&dst[cc * 8] = make_uint4(u[0], u[1], u[2], u[3]);
        }
        float* sdst = &Sk[arow * 68 + ah];
        #pragma unroll
        for (int cc = 0; cc < 8; ++cc)
            *(float4*)&sdst[cc * 4] = make_float4(skp[cc*4], skp[cc*4+1], skp[cc*4+2], skp[cc*4+3]);
    }
    __syncthreads();

    f32x4 acc[4][2];
    #pragma unroll
    for (int i = 0; i < 4; ++i)
        #pragma unroll
        for (int j = 0; j < 2; ++j) acc[i][j] = (f32x4)0.f;
    #pragma unroll
    for (int ks = 0; ks < 2; ++ks) {
        short8 a[4], b[2];
        #pragma unroll
        for (int mt = 0; mt < 4; ++mt)
            a[mt] = *(const short8*)&As[(wm + mt * 16 + r16) * 72 + ks * 32 + q * 8];
        #pragma unroll
        for (int nt = 0; nt < 2; ++nt)
            b[nt] = *(const short8*)&Bs[(wn + nt * 16 + r16) * 72 + ks * 32 + q * 8];
        #pragma unroll
        for (int mt = 0; mt < 4; ++mt)
            #pragma unroll
            for (int nt = 0; nt < 2; ++nt)
                acc[mt][nt] = __builtin_amdgcn_mfma_f32_16x16x32_bf16(a[mt], b[nt], acc[mt][nt], 0, 0, 0);
    }

    #pragma unroll
    for (int mt = 0; mt < 4; ++mt) {
        float sreg[4] = {0.f, 0.f, 0.f, 0.f};
        #pragma unroll
        for (int nt = 0; nt < 2; ++nt) {
            int n = wn + nt * 16 + r16;
            float bv = b2[kl * 64 + n];
            #pragma unroll
            for (int reg = 0; reg < 4; ++reg) {
                int lr = wm + mt * 16 + q * 4 + reg;
                float v = Sk[lr * 68 + n] + fmaxf(acc[mt][nt][reg] + bv, 0.f);
                xsum[(size_t)(bm + lr) * 2560 + kl * 64 + n] = v;
                sreg[reg] += v * v;
            }
        }
        #pragma unroll
        for (int reg = 0; reg < 4; ++reg) {
            float s = sreg[reg];
            s += __shfl_xor(s, 1); s += __shfl_xor(s, 2);
            s += __shfl_xor(s, 4); s += __shfl_xor(s, 8);
            if (r16 == 0) {
                int row = bm + wm + mt * 16 + q * 4 + reg;
                part8[(size_t)row * 80 + kl * 2 + half] = s;
            }
        }
    }
}

// ---------------------------------------------------------------------------
// Norm-argmax: first-max argmax per row; write ONLY the active 256-capsule
// slice of xrec (bf16) — the rest is never read by the grouped layer-1 GEMM.
// ---------------------------------------------------------------------------
__global__ __launch_bounds__(256) void mask_kernel(
    const float* __restrict__ xs, const float* __restrict__ part8,
    unsigned short* __restrict__ xrec, int* __restrict__ active)
{
    int b = blockIdx.x;
    int tid = threadIdx.x;
    __shared__ float norms[10];
    __shared__ int act_sh;
    if (tid < 10) {
        float s = 0.f;
        #pragma unroll
        for (int j = 0; j < 8; ++j) s += part8[(size_t)b * 80 + tid * 8 + j];
        norms[tid] = s;
    }
    __syncthreads();
    if (tid == 0) {
        int best = 0; float bn = -1.f;
        #pragma unroll
        for (int k = 0; k < 10; ++k)
            if (norms[k] > bn) { bn = norms[k]; best = k; }
        act_sh = best;
        active[b] = best;
    }
    __syncthreads();
    int act = act_sh;
    int idx = act * 256 + tid;
    xrec[(size_t)b * 2560 + idx] = f2bf(xs[(size_t)b * 2560 + idx]);
}

// ---------------------------------------------------------------------------
// Bucket rows by active capsule: perm[] (group-contiguous row order) +
// slot table (group, perm row start, valid rows) for the grouped GEMM grid.
// Max slots = floor(512/64) + 10 = 18.
// ---------------------------------------------------------------------------
__global__ __launch_bounds__(512) void bucket_kernel(
    const int* __restrict__ active, int* __restrict__ perm,
    int4* __restrict__ slots)
{
    __shared__ int cnt[10], pos[10];
    int tid = threadIdx.x;
    if (tid < 10) cnt[tid] = 0;
    __syncthreads();
    int a = active[tid];
    atomicAdd(&cnt[a], 1);
    __syncthreads();
    if (tid == 0) {
        int o = 0, s = 0;
        for (int g = 0; g < 10; ++g) {
            pos[g] = o;
            int mg = cnt[g];
            for (int t0 = 0; t0 < mg; t0 += 64)
                slots[s++] = make_int4(g, o + t0, min(64, mg - t0), 0);
            o += mg;
        }
        for (; s < 18; ++s) slots[s] = make_int4(0, 0, 0, 0);
    }
    __syncthreads();
    int r = atomicAdd(&pos[a], 1);
    perm[r] = tid;   // within-group order nondeterministic; un-permuted at the end
}

// ---------------------------------------------------------------------------
// Grouped MLP layer-1 GEMM: per slot (<=64 permuted rows, one capsule g),
// (m x 5120) @ Wt1[:, g*256 : g*256+256]^T with K=256. Tile 64m x 128n,
// BK=32, 4 waves (wave = 32m x 64n). Fused bias+relu -> h1 bf16 (permuted
// row space). Replaces the dense K=2560 split-K GEMM + combine (10x FLOPs).
// ---------------------------------------------------------------------------
__global__ __launch_bounds__(256) void gemm_l1(
    const unsigned short* __restrict__ xrec, const int* __restrict__ perm,
    const int4* __restrict__ slots, const unsigned short* __restrict__ Wt1,
    const float* __restrict__ br1, unsigned short* __restrict__ h1)
{
    int4 s = slots[blockIdx.y];
    if (s.z == 0) return;
    int g = s.x, mstart = s.y, mval = s.z;
    int bn = blockIdx.x * 128;
    int tid = threadIdx.x;

    __shared__ __align__(16) unsigned short As[64 * 32];
    __shared__ __align__(16) unsigned short Bs[128 * 32];
    __shared__ int rows[64];
    if (tid < 64) rows[tid] = perm[mstart + min(tid, mval - 1)];  // clamp: safe loads
    __syncthreads();

    int w = tid >> 6, lane = tid & 63;
    int wm = (w >> 1) * 32, wn = (w & 1) * 64;
    int q = lane >> 4, r16 = lane & 15;
    int srow = tid >> 2, skq = tid & 3;

    f32x4 acc[2][4];
    #pragma unroll
    for (int i = 0; i < 2; ++i)
        #pragma unroll
        for (int j = 0; j < 4; ++j) acc[i][j] = (f32x4)0.f;

    int arow = rows[srow];
    const unsigned short* ga = xrec + (size_t)arow * 2560 + g * 256 + skq * 8;
    const unsigned short* gb = Wt1 + (size_t)(bn + srow) * 2560 + g * 256 + skq * 8;

    for (int kk = 0; kk < 256; kk += 32) {
        GLD16(ga + kk, &As[tid * 8]);
        GLD16(gb + kk, &Bs[tid * 8]);
        GLD16(gb + kk + (size_t)64 * 2560, &Bs[(tid + 256) * 8]);
        __syncthreads();

        short8 a[2], b[4];
        #pragma unroll
        for (int mt = 0; mt < 2; ++mt)
            a[mt] = *(const short8*)&As[(wm + mt * 16 + r16) * 32 + q * 8];
        #pragma unroll
        for (int nt = 0; nt < 4; ++nt)
            b[nt] = *(const short8*)&Bs[(wn + nt * 16 + r16) * 32 + q * 8];
        #pragma unroll
        for (int mt = 0; mt < 2; ++mt)
            #pragma unroll
            for (int nt = 0; nt < 4; ++nt)
                acc[mt][nt] = __builtin_amdgcn_mfma_f32_16x16x32_bf16(a[mt], b[nt], acc[mt][nt], 0, 0, 0);
        __syncthreads();
    }

    // fused epilogue: bias + relu -> h1 bf16 (permuted row space)
    #pragma unroll
    for (int mt = 0; mt < 2; ++mt) {
        #pragma unroll
        for (int nt = 0; nt < 4; ++nt) {
            int n = bn + wn + nt * 16 + r16;
            float bv = (n < 5000) ? br1[n] : 0.f;
            #pragma unroll
            for (int reg = 0; reg < 4; ++reg) {
                int lm = wm + mt * 16 + q * 4 + reg;
                if (lm < mval)
                    h1[(size_t)(mstart + lm) * 5120 + n] =
                        f2bf(fmaxf(acc[mt][nt][reg] + bv, 0.f));
            }
        }
    }
}

// ---------------------------------------------------------------------------
// Split-K MFMA GEMM, 64(M)x128(N) tile, BK=32. 256 thr = 4 waves (2x2),
// each wave 32m x 64n = 2x4 frags of 16x16x32. Grid (Np/128, M/64, SPLITK).
// ---------------------------------------------------------------------------
#define SPLITK 4
__global__ __launch_bounds__(256) void gemm_splitk(
    const unsigned short* __restrict__ A, int ldA,
    const unsigned short* __restrict__ Bt, int ldB,
    float* __restrict__ P, int Np, int kper)
{
    __shared__ __align__(16) unsigned short As[64 * 32];
    __shared__ __align__(16) unsigned short Bs[128 * 32];

    int tid = threadIdx.x;
    int bn = blockIdx.x * 128;
    int bm = blockIdx.y * 64;
    int kz = blockIdx.z * kper;

    int w = tid >> 6, lane = tid & 63;
    int wm = (w >> 1) * 32, wn = (w & 1) * 64;
    int q = lane >> 4, r16 = lane & 15;

    int srow = tid >> 2, skq = tid & 3;   // staging chunk -> (row, 16B quarter)

    f32x4 acc[2][4];
    #pragma unroll
    for (int i = 0; i < 2; ++i)
        #pragma unroll
        for (int j = 0; j < 4; ++j) acc[i][j] = (f32x4)0.f;

    for (int kk = 0; kk < kper; kk += 32) {
        int k0 = kz + kk;
        const unsigned short* ga = A + (size_t)(bm + srow) * ldA + k0 + skq * 8;
        GLD16(ga, &As[tid * 8]);
        const unsigned short* gb = Bt + (size_t)(bn + srow) * ldB + k0 + skq * 8;
        GLD16(gb, &Bs[tid * 8]);
        GLD16(gb + (size_t)64 * ldB, &Bs[(tid + 256) * 8]);
        __syncthreads();

        short8 a[2], b[4];
        #pragma unroll
        for (int mt = 0; mt < 2; ++mt)
            a[mt] = *(const short8*)&As[(wm + mt * 16 + r16) * 32 + q * 8];
        #pragma unroll
        for (int nt = 0; nt < 4; ++nt)
            b[nt] = *(const short8*)&Bs[(wn + nt * 16 + r16) * 32 + q * 8];
        #pragma unroll
        for (int mt = 0; mt < 2; ++mt)
            #pragma unroll
            for (int nt = 0; nt < 4; ++nt)
                acc[mt][nt] = __builtin_amdgcn_mfma_f32_16x16x32_bf16(a[mt], b[nt], acc[mt][nt], 0, 0, 0);
        __syncthreads();
    }

    float* Pz = P + (size_t)blockIdx.z * 512 * Np;
    #pragma unroll
    for (int mt = 0; mt < 2; ++mt) {
        #pragma unroll
        for (int nt = 0; nt < 4; ++nt) {
            int cn = bn + wn + nt * 16 + r16;
            #pragma unroll
            for (int reg = 0; reg < 4; ++reg) {
                int cm = bm + wm + mt * 16 + q * 4 + reg;
                Pz[(size_t)cm * Np + cn] = acc[mt][nt][reg];
            }
        }
    }
}

// ---------------------------------------------------------------------------
// Combine split-K partials + bias + act. MODE 0: relu->bf16 (permuted rows
// kept permuted). MODE 1: sigmoid->f32, un-permute rows via perm[].
// ---------------------------------------------------------------------------
template<int MODE>
__global__ __launch_bounds__(256) void combine_kernel(
    const float* __restrict__ P, const float* __restrict__ bias,
    void* __restrict__ out, int Np, int N_real, const int* __restrict__ perm)
{
    int gid = blockIdx.x * 256 + threadIdx.x;
    int n0 = (gid * 4) % Np;
    int m  = (gid * 4) / Np;
    size_t MN = (size_t)512 * Np;
    const float* p = P + (size_t)m * Np + n0;
    f32x4 s = *(const f32x4*)p;
    s += *(const f32x4*)(p + MN);
    s += *(const f32x4*)(p + 2 * MN);
    s += *(const f32x4*)(p + 3 * MN);
    f32x4 bv = (n0 < N_real) ? *(const f32x4*)(bias + n0) : (f32x4)0.f;
    s += bv;
    if (MODE == 0) {
        unsigned int lo = (unsigned int)f2bf(fmaxf(s[0], 0.f)) | ((unsigned int)f2bf(fmaxf(s[1], 0.f)) << 16);
        unsigned int hi = (unsigned int)f2bf(fmaxf(s[2], 0.f)) | ((unsigned int)f2bf(fmaxf(s[3], 0.f)) << 16);
        *(uint2*)((unsigned short*)out + (size_t)m * Np + n0) = make_uint2(lo, hi);
    } else {
        int row = perm[m];   // un-permute at the very end
        f32x4 v;
        v[0] = 1.f / (1.f + expf(-s[0]));
        v[1] = 1.f / (1.f + expf(-s[1]));
        v[2] = 1.f / (1.f + expf(-s[2]));
        v[3] = 1.f / (1.f + expf(-s[3]));
        *(f32x4*)((float*)out + (size_t)row * Np + n0) = v;
    }
}

extern "C" void kernel_launch(void* const* d_in, const int* in_sizes, int n_in,
                              void* d_out, int out_size, void* d_ws, size_t ws_size,
                              hipStream_t stream) {
    const float* x   = (const float*)d_in[0];
    const float* C1  = (const float*)d_in[1];
    const float* W1  = (const float*)d_in[2];
    const float* b1  = (const float*)d_in[3];
    const float* Cs  = (const float*)d_in[4];
    const float* C2  = (const float*)d_in[5];
    const float* W2  = (const float*)d_in[6];
    const float* b2  = (const float*)d_in[7];
    const float* Wr1 = (const float*)d_in[8];
    const float* br1 = (const float*)d_in[9];
    const float* Wr2 = (const float*)d_in[10];
    const float* br2 = (const float*)d_in[11];
    const float* Wr3 = (const float*)d_in[12];
    const float* br3 = (const float*)d_in[13];

    float* out = (float*)d_out;
    float* out0     = out;              // (512,3072) f32 sigmoid output
    float* xsum_out = out + OUT0_SZ;    // (512,2560) f32 x_sum

    // workspace layout (bytes)
    char* base = (char*)d_ws;
    unsigned short* xrec  = (unsigned short*)(base);              //   2,621,440
    unsigned short* h1    = (unsigned short*)(base +   2621440);  //   5,242,880
    unsigned short* h2    = (unsigned short*)(base +   7864320);  //   4,194,304
    unsigned short* Wt1   = (unsigned short*)(base +  12058624);  //  26,214,400
    unsigned short* Wt2   = (unsigned short*)(base +  38273024);  //  41,943,040
    unsigned short* Wt3   = (unsigned short*)(base +  80216064);  //  25,165,824
    float*          Pbuf  = (float*)(base + 105381888);           //  <=33,554,432 used (L2/L3)
    unsigned short* xp    = (unsigned short*)(base + 147324928);  //   3,145,728
    unsigned short* W1t   = (unsigned short*)(base + 150470656);  //     393,216
    unsigned short* W2t   = (unsigned short*)(base + 150863872);  //     327,680
    float*          part8 = (float*)(base + 151191552);           //     163,840
    // small control arrays carved from Pbuf tail (layer2 uses only 33,554,432 B)
    int*  active = (int*)(base + 105381888 + 33554432);           //       2,048
    int*  perm   = active + 512;                                  //       2,048
    int4* slots  = (int4*)(perm + 512);                           //         288

    // prep: all weight transposes, pipelined 4 tiles/block
    convT_all<<<2870, 256, 0, stream>>>(Wr1, Wt1, Wr2, Wt2, Wr3, Wt3,
                                        W1, W1t, W2, W2t);

    // capsule path: pooled MFMA GEMMs (C is 0/1 -> sparse pooling)
    caps_gemm1<<<dim3(48, 4), 256, 0, stream>>>(x, C1, W1t, b1, xp);
    caps_gemm2<<<dim3(40, 4), 256, 0, stream>>>(xp, Cs, C2, W2t, b2, xsum_out, part8);
    mask_kernel<<<BATCH, 256, 0, stream>>>(xsum_out, part8, xrec, active);
    bucket_kernel<<<1, 512, 0, stream>>>(active, perm, slots);

    // --- MLP layer 1 (grouped, K=256): (512,256)@Wt1-slice -> h1 (512,5120 bf16, permuted rows) ---
    gemm_l1<<<dim3(5120 / 128, 18), 256, 0, stream>>>(xrec, perm, slots, Wt1, br1, h1);

    // --- MLP layer 2: (512,5120) @ (5120,4000) -> h2 (512,4096 bf16, permuted) ---
    gemm_splitk<<<dim3(4096 / 128, 8, SPLITK), 256, 0, stream>>>(h1, 5120, Wt2, 5120, Pbuf, 4096, 5120 / SPLITK);
    combine_kernel<0><<<512 * 4096 / 1024, 256, 0, stream>>>(Pbuf, br2, h2, 4096, 4000, nullptr);

    // --- MLP layer 3: (512,4096) @ (4096,3072) -> out0 (512,3072 f32, un-permuted) ---
    gemm_splitk<<<dim3(3072 / 128, 8, SPLITK), 256, 0, stream>>>(h2, 4096, Wt3, 4096, Pbuf, 3072, 4096 / SPLITK);
    combine_kernel<1><<<512 * 3072 / 1024, 256, 0, stream>>>(Pbuf, br3, out0, 3072, 3072, perm);
}